// Round 4
// baseline (109.719 us; speedup 1.0000x reference)
//
#include <hip/hip_runtime.h>
#include <hip/hip_bf16.h>

// ---------------- problem constants ----------------
#define Bn    8
#define MO    12
#define Dd    512
#define NOBJ  37
#define NACT  6
#define NTRS  3
#define EMB   128
#define NAA   100
#define NCLS  300
#define Kk    72            // MO*NACT
#define Pp    5112          // Kk*(Kk-1)
#define HALF  768           // Dd + 2*EMB
#define FD    1536          // 2*HALF

// output layout (concatenated return order)
#define OUT_FINAL 0
#define OUT_PLOG  (Bn*NCLS)                       // 2400
#define OUT_TTGT  (OUT_PLOG + Bn*Pp*NTRS)         // 125088
#define OUT_ACT   (OUT_TTGT + Bn*Pp*NTRS)         // 247776
#define OUT_OBJ   (OUT_ACT + Bn*Kk)               // 248352

// ---------------- workspace layout (4-byte units) ----------------
#define WS_LINP 0                                 // [B,MO,6] (th = t*2+h)
#define WS_EO   (WS_LINP + Bn*MO*6)               // [NOBJ,6]        576
#define WS_EA   (WS_EO + NOBJ*6)                  // [NACT,6]        798
#define WS_INV  (WS_EA + NACT*6)                  // [3]             834
#define WS_NE   840                               // [B,NCLS]
#define WS_OBJ  (WS_NE + Bn*NCLS)                 // [B,MO,NOBJ]    3240
#define WS_ACT  (WS_OBJ + Bn*MO*NOBJ)             // [B,K]          6792
#define WS_SEG  (WS_ACT + Bn*Kk)                  // [B,NCLS] u32   7368
#define WS_CNT  (WS_SEG + Bn*NCLS)                // [B] u32        9768  (contiguous w/ SEG for zeroing)
#define NZERO   (Bn*NCLS + Bn)                    // 2408 u32 to zero

// monotonic float <-> uint; 0u is below any finite mapped value = "empty"
__device__ __forceinline__ unsigned fmap(float f) {
  unsigned u = __float_as_uint(f);
  return (u & 0x80000000u) ? ~u : (u | 0x80000000u);
}
__device__ __forceinline__ float funmap(unsigned u) {
  return __uint_as_float((u & 0x80000000u) ? (u & 0x7fffffffu) : ~u);
}

__device__ __forceinline__ float wreduce(float v) {
#pragma unroll
  for (int off = 32; off > 0; off >>= 1) v += __shfl_xor(v, off, 64);
  return v;
}

// 512-dot with x preloaded (lane holds float4 #lane, #(lane+64))
__device__ __forceinline__ float dotW(const float* __restrict__ wrow,
                                      float4 x0, float4 x1, int lane) {
  const float4* w4 = (const float4*)wrow;
  float4 w0 = w4[lane], w1 = w4[lane + 64];
  float s0 = fmaf(w0.x, x0.x, fmaf(w0.y, x0.y, fmaf(w0.z, x0.z, w0.w * x0.w)));
  float s1 = fmaf(w1.x, x1.x, fmaf(w1.y, x1.y, fmaf(w1.z, x1.z, w1.w * x1.w)));
  return wreduce(s0 + s1);
}

__device__ __forceinline__ float dot512_wave(const float* __restrict__ a,
                                             const float* __restrict__ b, int lane) {
  const float4* b4 = (const float4*)b;
  return dotW(a, b4[lane], b4[lane + 64], lane);
}

__device__ __forceinline__ float dot128_wave(const float* __restrict__ a,
                                             const float* __restrict__ b, int lane) {
  const float2* a2 = (const float2*)a;
  const float2* b2 = (const float2*)b;
  float2 x = a2[lane], y = b2[lane];
  return wreduce(fmaf(x.x, y.x, x.y * y.y));
}

// ---------------- K1: one minimal task per wave, zero dependencies ----------------
#define W_OBJ_E  (Bn*MO*NOBJ)             // 3552
#define W_ACT_E  (W_OBJ_E + Bn*Kk)        // 4128
#define W_LINP_E (W_ACT_E + Bn*MO*6)      // 4704
#define W_EO_E   (W_LINP_E + NOBJ*6)      // 4926
#define W_EA_E   (W_EO_E + NACT*6)        // 4962
#define W_INV_E  (W_EA_E + NTRS)          // 4965
#define W_NE_E   (W_INV_E + Bn*NCLS)      // 7365
#define W_TOT    (W_NE_E + 38)            // 7403 (38*64=2432 >= NZERO)

__global__ __launch_bounds__(256) void k1(
    const float* __restrict__ inp, const float* __restrict__ objmask,
    const float* __restrict__ W_obj, const float* __restrict__ b_obj,
    const float* __restrict__ W_act, const float* __restrict__ b_act,
    const float* __restrict__ W_tr, const float* __restrict__ b_tr,
    const float* __restrict__ W_ne, const float* __restrict__ b_ne,
    const float* __restrict__ obj_emb, const float* __restrict__ act_emb,
    float* __restrict__ out, float* __restrict__ ws)
{
  int gt = blockIdx.x * 256 + threadIdx.x;
  int w = gt >> 6, lane = gt & 63;

  if (w < W_OBJ_E) {
    int b = w / (MO*NOBJ), r = w % (MO*NOBJ), o = r / NOBJ, c = r % NOBJ;
    float v = dot512_wave(W_obj + c*Dd, inp + (b*MO + o)*Dd, lane) + b_obj[c];
    if (!lane) { out[OUT_OBJ + (b*MO + o)*NOBJ + c] = v; ws[WS_OBJ + (b*MO + o)*NOBJ + c] = v; }
  } else if (w < W_ACT_E) {
    int r = w - W_OBJ_E, b = r / Kk, k = r % Kk, o = k / NACT, a = k % NACT;
    float v = dot512_wave(W_act + a*Dd, inp + (b*MO + o)*Dd, lane) + b_act[a];
    if (!lane) { out[OUT_ACT + b*Kk + k] = v; ws[WS_ACT + b*Kk + k] = v; }
  } else if (w < W_LINP_E) {
    int r = w - W_ACT_E, b = r / (MO*6), r2 = r % (MO*6), o = r2 / 6, th = r2 % 6;
    int t = th >> 1, h = th & 1;
    float v = dot512_wave(W_tr + t*FD + h*HALF, inp + (b*MO + o)*Dd, lane);
    if (!lane) ws[WS_LINP + (b*MO + o)*6 + th] = v;
  } else if (w < W_EO_E) {
    int r = w - W_LINP_E, oc = r / 6, th = r % 6, t = th >> 1, h = th & 1;
    float v = dot128_wave(W_tr + t*FD + h*HALF + Dd, obj_emb + oc*EMB, lane);
    if (!lane) ws[WS_EO + oc*6 + th] = v;
  } else if (w < W_INV_E) {
    if (w < W_EA_E) {
      int r = w - W_EO_E, a = r / 6, th = r % 6, t = th >> 1, h = th & 1;
      float v = dot128_wave(W_tr + t*FD + h*HALF + Dd + EMB, act_emb + a*EMB, lane);
      if (!lane) ws[WS_EA + a*6 + th] = v;
    } else {
      int t = w - W_EA_E;
      const float4* w4 = (const float4*)(W_tr + t*FD);
      float s = 0.f;
#pragma unroll
      for (int i = 0; i < 6; ++i) { float4 x = w4[lane + 64*i]; s += x.x + x.y + x.z + x.w; }
      s = wreduce(s);
      if (!lane) ws[WS_INV + t] = b_tr[t] - s;        // all-(-1) pair-row logit
    }
  } else if (w < W_NE_E) {
    // one wave per (b,c): masked-mean pool inline (L2-hot), then W_ne dot
    int r = w - W_INV_E, b = r / NCLS, c = r % NCLS;
    const float4* i4 = (const float4*)inp;
    float msum = 0.f;
    float4 p0 = make_float4(0.f, 0.f, 0.f, 0.f), p1 = p0;
#pragma unroll
    for (int o = 0; o < MO; ++o) {
      float m = objmask[b*MO + o];
      msum += m;
      float4 v0 = i4[(b*MO + o)*128 + lane];
      float4 v1 = i4[(b*MO + o)*128 + lane + 64];
      p0.x = fmaf(m, v0.x, p0.x); p0.y = fmaf(m, v0.y, p0.y);
      p0.z = fmaf(m, v0.z, p0.z); p0.w = fmaf(m, v0.w, p0.w);
      p1.x = fmaf(m, v1.x, p1.x); p1.y = fmaf(m, v1.y, p1.y);
      p1.z = fmaf(m, v1.z, p1.z); p1.w = fmaf(m, v1.w, p1.w);
    }
    float v = dotW(W_ne + c*Dd, p0, p1, lane) / msum + b_ne[c];
    if (!lane) ws[WS_NE + b*NCLS + c] = v;
  } else if (w < W_TOT) {
    int idx = (w - W_NE_E)*64 + lane;
    if (idx < NZERO) ((unsigned*)ws)[WS_SEG + idx] = 0u;   // segmax + counters
  }
}

// ---------------- K2: preamble (argmax/sel) + pair loop + last-block merge ----
#define NSLICE 20

__global__ __launch_bounds__(256) void k2(
    const float* __restrict__ objmask, const float* __restrict__ TRt,
    const float* __restrict__ b_tr, const int* __restrict__ AA,
    const int* __restrict__ aalut,
    float* __restrict__ out, float* __restrict__ ws)
{
  __shared__ float s_L[Kk*6];              // [k][t*2+h], h==0 half includes b_tr
  __shared__ float s_inv[NTRS];
  __shared__ int s_sel[Kk], s_aa[Kk], s_C[Kk], s_pred[MO], s_T, s_last;

  int b = blockIdx.x / NSLICE, slice = blockIdx.x % NSLICE;
  int tid = threadIdx.x;

  // ---- preamble: per-block redundant argmax + selection (cheap, L2-hot) ----
  if (tid < MO) {                          // obj argmax, first-max
    const float* p = ws + WS_OBJ + (b*MO + tid)*NOBJ;
    float best = p[0]; int bi = 0;
    for (int c = 1; c < NOBJ; ++c) { float v = p[c]; if (v > best) { best = v; bi = c; } }
    s_pred[tid] = bi;
  } else if (tid < MO + NTRS) {
    s_inv[tid - MO] = ws[WS_INV + (tid - MO)];
  } else if (tid >= 64 && tid < 64 + Kk) { // selection flags (separate wave)
    int k = tid - 64, o = k / NACT;
    int aa = AA[b*Kk + k];
    // sigmoid(x)>0.5 <=> x>0 ; pred_act==1.0 also needs mask==1.0
    int sel = (ws[WS_ACT + b*Kk + k] > 0.f) && (objmask[b*MO + o] == 1.0f) && (aa != -1);
    s_sel[k] = sel;
    s_aa[k] = sel ? aa : -1;
  }
  __syncthreads();
  for (int m = tid; m < Kk*6; m += 256) {  // assemble half-logits
    int k = m / 6, th = m % 6, t = th >> 1, h = th & 1;
    int o = k / NACT, a = k % NACT;
    float v = ws[WS_LINP + (b*MO + o)*6 + th] + ws[WS_EO + s_pred[o]*6 + th]
            + ws[WS_EA + a*6 + th];
    if (h == 0) v += b_tr[t];
    s_L[m] = v;
  }
  if (tid == 0) {
    int c = 0;
    for (int k = 0; k < Kk; ++k) { s_C[k] = c; c += s_sel[k]; }
    s_T = c;
  }
  __syncthreads();

  // ---- pair phase: closed-form packed destination ----
  int T = s_T, Vtot = T*(T-1);
  int q = slice*256 + tid;
  if (q < Pp) {
    float* plog = out + OUT_PLOG + (size_t)b*Pp*NTRS;
    float* ttgt = out + OUT_TTGT + (size_t)b*Pp*NTRS;
    int i = q / (Kk-1);
    int jj = q - i*(Kk-1);
    int j = jj + (jj >= i ? 1 : 0);
    int si = s_sel[i], sj = s_sel[j];
    int vb = s_C[i]*(T-1) + (si ? (s_C[j] - (i < j ? 1 : 0)) : 0);
    bool valid = si && sj;
    int pos = valid ? vb : (Vtot + q - vb);
    float l0, l1, l2;
    if (valid) {
      l0 = s_L[i*6+0] + s_L[j*6+1];
      l1 = s_L[i*6+2] + s_L[j*6+3];
      l2 = s_L[i*6+4] + s_L[j*6+5];
    } else { l0 = s_inv[0]; l1 = s_inv[1]; l2 = s_inv[2]; }
    int ob = pos*3;
    plog[ob+0] = l0; plog[ob+1] = l1; plog[ob+2] = l2;
    if (valid) {
      const float* tr = TRt + (((size_t)b*Kk + i)*Kk + j)*NTRS;
      ttgt[ob+0] = tr[0]; ttgt[ob+1] = tr[1]; ttgt[ob+2] = tr[2];
      int base = (s_aa[i]*NAA + s_aa[j])*NTRS;
      unsigned* seg = (unsigned*)ws + WS_SEG + b*NCLS;
      atomicMax(&seg[aalut[base+0]], fmap(l0));
      atomicMax(&seg[aalut[base+1]], fmap(l1));
      atomicMax(&seg[aalut[base+2]], fmap(l2));
    } else {
      ttgt[ob+0] = -1.f; ttgt[ob+1] = -1.f; ttgt[ob+2] = -1.f;
    }
  }

  // ---- last block for this batch merges segmax with non_exist ----
  __threadfence();                         // make this thread's atomics visible
  __syncthreads();
  if (tid == 0) {
    unsigned old = atomicAdd((unsigned*)ws + WS_CNT + b, 1u);
    s_last = (old == NSLICE - 1);
  }
  __syncthreads();
  if (s_last) {
    __threadfence();                       // acquire
    for (int c = tid; c < NCLS; c += 256) {
      // atomicMax(p,0) = device-scope L2 read (no stale L1)
      unsigned u = atomicMax((unsigned*)ws + WS_SEG + b*NCLS + c, 0u);
      out[OUT_FINAL + b*NCLS + c] = u ? funmap(u) : ws[WS_NE + b*NCLS + c];
    }
  }
}

extern "C" void kernel_launch(void* const* d_in, const int* in_sizes, int n_in,
                              void* d_out, int out_size, void* d_ws, size_t ws_size,
                              hipStream_t stream) {
  (void)in_sizes; (void)n_in; (void)ws_size; (void)out_size;
  const float* inp      = (const float*)d_in[0];
  const float* objmask  = (const float*)d_in[1];
  const float* TRt      = (const float*)d_in[2];
  const float* W_obj    = (const float*)d_in[3];
  const float* b_obj    = (const float*)d_in[4];
  const float* W_act    = (const float*)d_in[5];
  const float* b_act    = (const float*)d_in[6];
  const float* W_tr     = (const float*)d_in[7];
  const float* b_tr     = (const float*)d_in[8];
  const float* W_ne     = (const float*)d_in[9];
  const float* b_ne     = (const float*)d_in[10];
  const float* obj_emb  = (const float*)d_in[11];
  const float* act_emb  = (const float*)d_in[12];
  const int*   AA       = (const int*)d_in[13];
  // d_in[14] = obj_act_lookup (eval-only)
  const int*   aalut    = (const int*)d_in[15];
  float* out = (float*)d_out;
  float* ws  = (float*)d_ws;

  hipLaunchKernelGGL(k1, dim3((W_TOT + 3) / 4), dim3(256), 0, stream,
                     inp, objmask, W_obj, b_obj, W_act, b_act, W_tr, b_tr,
                     W_ne, b_ne, obj_emb, act_emb, out, ws);
  hipLaunchKernelGGL(k2, dim3(Bn * NSLICE), dim3(256), 0, stream,
                     objmask, TRt, b_tr, AA, aalut, out, ws);
}

// Round 5
// 103.935 us; speedup vs baseline: 1.0557x; 1.0557x over previous
//
#include <hip/hip_runtime.h>
#include <hip/hip_bf16.h>

// ---------------- problem constants ----------------
#define Bn    8
#define MO    12
#define Dd    512
#define NOBJ  37
#define NACT  6
#define NTRS  3
#define EMB   128
#define NAA   100
#define NCLS  300
#define Kk    72            // MO*NACT
#define Pp    5112          // Kk*(Kk-1)
#define HALF  768           // Dd + 2*EMB
#define FD    1536          // 2*HALF

// output layout (concatenated return order)
#define OUT_FINAL 0
#define OUT_PLOG  (Bn*NCLS)                       // 2400
#define OUT_TTGT  (OUT_PLOG + Bn*Pp*NTRS)         // 125088
#define OUT_ACT   (OUT_TTGT + Bn*Pp*NTRS)         // 247776
#define OUT_OBJ   (OUT_ACT + Bn*Kk)               // 248352

// ---------------- workspace layout (4-byte units) ----------------
#define WS_LINP 0                                 // [B,MO,6] (th = t*2+h)
#define WS_EO   (WS_LINP + Bn*MO*6)               // [NOBJ,6]        576
#define WS_EA   (WS_EO + NOBJ*6)                  // [NACT,6]        798
#define WS_INV  (WS_EA + NACT*6)                  // [3]             834
#define WS_NE   840                               // [B,NCLS]
#define WS_OBJ  (WS_NE + Bn*NCLS)                 // [B,MO,NOBJ]    3240
#define WS_ACT  (WS_OBJ + Bn*MO*NOBJ)             // [B,K]          6792

// monotonic float <-> uint; 0u is below any finite mapped value = "empty"
__device__ __forceinline__ unsigned fmap(float f) {
  unsigned u = __float_as_uint(f);
  return (u & 0x80000000u) ? ~u : (u | 0x80000000u);
}
__device__ __forceinline__ float funmap(unsigned u) {
  return __uint_as_float((u & 0x80000000u) ? (u & 0x7fffffffu) : ~u);
}

__device__ __forceinline__ float wreduce(float v) {
#pragma unroll
  for (int off = 32; off > 0; off >>= 1) v += __shfl_xor(v, off, 64);
  return v;
}

// 512-dot with x preloaded (lane holds float4 #lane, #(lane+64))
__device__ __forceinline__ float dotW(const float* __restrict__ wrow,
                                      float4 x0, float4 x1, int lane) {
  const float4* w4 = (const float4*)wrow;
  float4 w0 = w4[lane], w1 = w4[lane + 64];
  float s0 = fmaf(w0.x, x0.x, fmaf(w0.y, x0.y, fmaf(w0.z, x0.z, w0.w * x0.w)));
  float s1 = fmaf(w1.x, x1.x, fmaf(w1.y, x1.y, fmaf(w1.z, x1.z, w1.w * x1.w)));
  return wreduce(s0 + s1);
}

__device__ __forceinline__ float dot512_wave(const float* __restrict__ a,
                                             const float* __restrict__ b, int lane) {
  const float4* b4 = (const float4*)b;
  return dotW(a, b4[lane], b4[lane + 64], lane);
}

__device__ __forceinline__ float dot128_wave(const float* __restrict__ a,
                                             const float* __restrict__ b, int lane) {
  const float2* a2 = (const float2*)a;
  const float2* b2 = (const float2*)b;
  float2 x = a2[lane], y = b2[lane];
  return wreduce(fmaf(x.x, y.x, x.y * y.y));
}

// ---------------- K1: one minimal task per wave, zero dependencies ----------------
// No fences, no serial multi-dot loops, nothing to zero (segmax lives in K2's LDS).
#define W_OBJ_E  (Bn*MO*NOBJ)             // 3552
#define W_ACT_E  (W_OBJ_E + Bn*Kk)        // 4128
#define W_LINP_E (W_ACT_E + Bn*MO*6)      // 4704
#define W_EO_E   (W_LINP_E + NOBJ*6)      // 4926
#define W_EA_E   (W_EO_E + NACT*6)        // 4962
#define W_INV_E  (W_EA_E + NTRS)          // 4965
#define W_TOT    (W_INV_E + Bn*NCLS)      // 7365

__global__ __launch_bounds__(256) void k1(
    const float* __restrict__ inp, const float* __restrict__ objmask,
    const float* __restrict__ W_obj, const float* __restrict__ b_obj,
    const float* __restrict__ W_act, const float* __restrict__ b_act,
    const float* __restrict__ W_tr, const float* __restrict__ b_tr,
    const float* __restrict__ W_ne, const float* __restrict__ b_ne,
    const float* __restrict__ obj_emb, const float* __restrict__ act_emb,
    float* __restrict__ out, float* __restrict__ ws)
{
  int gt = blockIdx.x * 256 + threadIdx.x;
  int w = gt >> 6, lane = gt & 63;

  if (w < W_OBJ_E) {
    int b = w / (MO*NOBJ), r = w % (MO*NOBJ), o = r / NOBJ, c = r % NOBJ;
    float v = dot512_wave(W_obj + c*Dd, inp + (b*MO + o)*Dd, lane) + b_obj[c];
    if (!lane) { out[OUT_OBJ + (b*MO + o)*NOBJ + c] = v; ws[WS_OBJ + (b*MO + o)*NOBJ + c] = v; }
  } else if (w < W_ACT_E) {
    int r = w - W_OBJ_E, b = r / Kk, k = r % Kk, o = k / NACT, a = k % NACT;
    float v = dot512_wave(W_act + a*Dd, inp + (b*MO + o)*Dd, lane) + b_act[a];
    if (!lane) { out[OUT_ACT + b*Kk + k] = v; ws[WS_ACT + b*Kk + k] = v; }
  } else if (w < W_LINP_E) {
    int r = w - W_ACT_E, b = r / (MO*6), r2 = r % (MO*6), o = r2 / 6, th = r2 % 6;
    int t = th >> 1, h = th & 1;
    float v = dot512_wave(W_tr + t*FD + h*HALF, inp + (b*MO + o)*Dd, lane);
    if (!lane) ws[WS_LINP + (b*MO + o)*6 + th] = v;
  } else if (w < W_EO_E) {
    int r = w - W_LINP_E, oc = r / 6, th = r % 6, t = th >> 1, h = th & 1;
    float v = dot128_wave(W_tr + t*FD + h*HALF + Dd, obj_emb + oc*EMB, lane);
    if (!lane) ws[WS_EO + oc*6 + th] = v;
  } else if (w < W_INV_E) {
    if (w < W_EA_E) {
      int r = w - W_EO_E, a = r / 6, th = r % 6, t = th >> 1, h = th & 1;
      float v = dot128_wave(W_tr + t*FD + h*HALF + Dd + EMB, act_emb + a*EMB, lane);
      if (!lane) ws[WS_EA + a*6 + th] = v;
    } else {
      int t = w - W_EA_E;
      const float4* w4 = (const float4*)(W_tr + t*FD);
      float s = 0.f;
#pragma unroll
      for (int i = 0; i < 6; ++i) { float4 x = w4[lane + 64*i]; s += x.x + x.y + x.z + x.w; }
      s = wreduce(s);
      if (!lane) ws[WS_INV + t] = b_tr[t] - s;        // all-(-1) pair-row logit
    }
  } else if (w < W_TOT) {
    // one wave per (b,c): masked-mean pool inline (consecutive waves share b ->
    // L1-resident inp rows), then W_ne dot
    int r = w - W_INV_E, b = r / NCLS, c = r % NCLS;
    const float4* i4 = (const float4*)inp;
    float msum = 0.f;
    float4 p0 = make_float4(0.f, 0.f, 0.f, 0.f), p1 = p0;
#pragma unroll
    for (int o = 0; o < MO; ++o) {
      float m = objmask[b*MO + o];
      msum += m;
      float4 v0 = i4[(b*MO + o)*128 + lane];
      float4 v1 = i4[(b*MO + o)*128 + lane + 64];
      p0.x = fmaf(m, v0.x, p0.x); p0.y = fmaf(m, v0.y, p0.y);
      p0.z = fmaf(m, v0.z, p0.z); p0.w = fmaf(m, v0.w, p0.w);
      p1.x = fmaf(m, v1.x, p1.x); p1.y = fmaf(m, v1.y, p1.y);
      p1.z = fmaf(m, v1.z, p1.z); p1.w = fmaf(m, v1.w, p1.w);
    }
    float v = dotW(W_ne + c*Dd, p0, p1, lane) / msum + b_ne[c];
    if (!lane) ws[WS_NE + b*NCLS + c] = v;
  }
}

// ---------------- K2: one block per batch; LDS segmax; no fences ----------------
__global__ __launch_bounds__(256) void k2(
    const float* __restrict__ objmask, const float* __restrict__ TRt,
    const float* __restrict__ b_tr, const int* __restrict__ AA,
    const int* __restrict__ aalut,
    float* __restrict__ out, float* __restrict__ ws)
{
  __shared__ float s_L[Kk*6];              // [k][t*2+h], h==0 half includes b_tr
  __shared__ float s_inv[NTRS];
  __shared__ unsigned s_seg[NCLS];
  __shared__ int s_sel[Kk], s_aa[Kk], s_C[Kk], s_pred[MO], s_T;

  int b = blockIdx.x;
  int tid = threadIdx.x;

  // ---- preamble (once per batch) ----
  if (tid < MO) {                          // obj argmax, first-max
    const float* p = ws + WS_OBJ + (b*MO + tid)*NOBJ;
    float best = p[0]; int bi = 0;
#pragma unroll
    for (int c = 1; c < NOBJ; ++c) { float v = p[c]; if (v > best) { best = v; bi = c; } }
    s_pred[tid] = bi;
  } else if (tid >= 64 && tid < 64 + Kk) { // selection flags
    int k = tid - 64, o = k / NACT;
    int aa = AA[b*Kk + k];
    // sigmoid(x)>0.5 <=> x>0 ; pred_act==1.0 also needs mask==1.0
    int sel = (ws[WS_ACT + b*Kk + k] > 0.f) && (objmask[b*MO + o] == 1.0f) && (aa != -1);
    s_sel[k] = sel;
    s_aa[k] = sel ? aa : -1;
  } else if (tid >= 192 && tid < 192 + NTRS) {
    s_inv[tid - 192] = ws[WS_INV + (tid - 192)];
  }
  for (int c = tid; c < NCLS; c += 256) s_seg[c] = 0u;
  __syncthreads();
  for (int m = tid; m < Kk*6; m += 256) {  // assemble half-logits
    int k = m / 6, th = m % 6, t = th >> 1, h = th & 1;
    int o = k / NACT, a = k % NACT;
    float v = ws[WS_LINP + (b*MO + o)*6 + th] + ws[WS_EO + s_pred[o]*6 + th]
            + ws[WS_EA + a*6 + th];
    if (h == 0) v += b_tr[t];
    s_L[m] = v;
  }
  if (tid == 0) {
    int c = 0;
    for (int k = 0; k < Kk; ++k) { s_C[k] = c; c += s_sel[k]; }
    s_T = c;
  }
  __syncthreads();

  // ---- pair phase: closed-form packed destination, 20 pairs/thread ----
  int T = s_T, Vtot = T*(T-1);
  float* plog = out + OUT_PLOG + (size_t)b*Pp*NTRS;
  float* ttgt = out + OUT_TTGT + (size_t)b*Pp*NTRS;
  for (int q = tid; q < Pp; q += 256) {
    int i = q / (Kk-1);
    int jj = q - i*(Kk-1);
    int j = jj + (jj >= i ? 1 : 0);
    int si = s_sel[i], sj = s_sel[j];
    // # valid pairs strictly before (i,j) in lex order -> O(1) packed position
    int vb = s_C[i]*(T-1) + (si ? (s_C[j] - (i < j ? 1 : 0)) : 0);
    bool valid = si && sj;
    int pos = valid ? vb : (Vtot + q - vb);
    float l0, l1, l2;
    if (valid) {
      l0 = s_L[i*6+0] + s_L[j*6+1];
      l1 = s_L[i*6+2] + s_L[j*6+3];
      l2 = s_L[i*6+4] + s_L[j*6+5];
    } else { l0 = s_inv[0]; l1 = s_inv[1]; l2 = s_inv[2]; }
    int ob = pos*3;
    plog[ob+0] = l0; plog[ob+1] = l1; plog[ob+2] = l2;
    if (valid) {
      const float* tr = TRt + (((size_t)b*Kk + i)*Kk + j)*NTRS;
      ttgt[ob+0] = tr[0]; ttgt[ob+1] = tr[1]; ttgt[ob+2] = tr[2];
      int base = (s_aa[i]*NAA + s_aa[j])*NTRS;
      atomicMax(&s_seg[aalut[base+0]], fmap(l0));   // ds_max_u32, LDS-local
      atomicMax(&s_seg[aalut[base+1]], fmap(l1));
      atomicMax(&s_seg[aalut[base+2]], fmap(l2));
    } else {
      ttgt[ob+0] = -1.f; ttgt[ob+1] = -1.f; ttgt[ob+2] = -1.f;
    }
  }
  __syncthreads();

  // ---- merge: exist ? seg_max : non_exist ----
  for (int c = tid; c < NCLS; c += 256) {
    unsigned u = s_seg[c];
    out[OUT_FINAL + b*NCLS + c] = u ? funmap(u) : ws[WS_NE + b*NCLS + c];
  }
}

extern "C" void kernel_launch(void* const* d_in, const int* in_sizes, int n_in,
                              void* d_out, int out_size, void* d_ws, size_t ws_size,
                              hipStream_t stream) {
  (void)in_sizes; (void)n_in; (void)ws_size; (void)out_size;
  const float* inp      = (const float*)d_in[0];
  const float* objmask  = (const float*)d_in[1];
  const float* TRt      = (const float*)d_in[2];
  const float* W_obj    = (const float*)d_in[3];
  const float* b_obj    = (const float*)d_in[4];
  const float* W_act    = (const float*)d_in[5];
  const float* b_act    = (const float*)d_in[6];
  const float* W_tr     = (const float*)d_in[7];
  const float* b_tr     = (const float*)d_in[8];
  const float* W_ne     = (const float*)d_in[9];
  const float* b_ne     = (const float*)d_in[10];
  const float* obj_emb  = (const float*)d_in[11];
  const float* act_emb  = (const float*)d_in[12];
  const int*   AA       = (const int*)d_in[13];
  // d_in[14] = obj_act_lookup (eval-only)
  const int*   aalut    = (const int*)d_in[15];
  float* out = (float*)d_out;
  float* ws  = (float*)d_ws;

  hipLaunchKernelGGL(k1, dim3((W_TOT + 3) / 4), dim3(256), 0, stream,
                     inp, objmask, W_obj, b_obj, W_act, b_act, W_tr, b_tr,
                     W_ne, b_ne, obj_emb, act_emb, out, ws);
  hipLaunchKernelGGL(k2, dim3(Bn), dim3(256), 0, stream,
                     objmask, TRt, b_tr, AA, aalut, out, ws);
}

// Round 6
// 98.906 us; speedup vs baseline: 1.1093x; 1.0508x over previous
//
#include <hip/hip_runtime.h>
#include <hip/hip_bf16.h>

// ---------------- problem constants ----------------
#define Bn    8
#define MO    12
#define Dd    512
#define NOBJ  37
#define NACT  6
#define NTRS  3
#define EMB   128
#define NAA   100
#define NCLS  300
#define Kk    72            // MO*NACT
#define Pp    5112          // Kk*(Kk-1)
#define HALF  768           // Dd + 2*EMB
#define FD    1536          // 2*HALF

// output layout (concatenated return order)
#define OUT_FINAL 0
#define OUT_PLOG  (Bn*NCLS)                       // 2400
#define OUT_TTGT  (OUT_PLOG + Bn*Pp*NTRS)         // 125088
#define OUT_ACT   (OUT_TTGT + Bn*Pp*NTRS)         // 247776
#define OUT_OBJ   (OUT_ACT + Bn*Kk)               // 248352

// ---------------- workspace layout (4-byte units) ----------------
#define WS_LINP 0                                 // [B,MO,6] (th = t*2+h)
#define WS_EO   (WS_LINP + Bn*MO*6)               // [NOBJ,6]        576
#define WS_EA   (WS_EO + NOBJ*6)                  // [NACT,6]        798
#define WS_INV  (WS_EA + NACT*6)                  // [3]             834
#define WS_NE   840                               // [B,NCLS]
#define WS_OBJ  (WS_NE + Bn*NCLS)                 // [B,MO,NOBJ]    3240
#define WS_ACT  (WS_OBJ + Bn*MO*NOBJ)             // [B,K]          6792
#define WS_SEG  (WS_ACT + Bn*Kk)                  // [B,NCLS] u32   7368
#define NZERO   (Bn*NCLS)                         // 2400 u32 to zero

// monotonic float <-> uint; 0u is below any finite mapped value = "empty"
__device__ __forceinline__ unsigned fmap(float f) {
  unsigned u = __float_as_uint(f);
  return (u & 0x80000000u) ? ~u : (u | 0x80000000u);
}
__device__ __forceinline__ float funmap(unsigned u) {
  return __uint_as_float((u & 0x80000000u) ? (u & 0x7fffffffu) : ~u);
}

__device__ __forceinline__ float wreduce(float v) {
#pragma unroll
  for (int off = 32; off > 0; off >>= 1) v += __shfl_xor(v, off, 64);
  return v;
}

// 512-dot with x preloaded (lane holds float4 #lane, #(lane+64))
__device__ __forceinline__ float dotW(const float* __restrict__ wrow,
                                      float4 x0, float4 x1, int lane) {
  const float4* w4 = (const float4*)wrow;
  float4 w0 = w4[lane], w1 = w4[lane + 64];
  float s0 = fmaf(w0.x, x0.x, fmaf(w0.y, x0.y, fmaf(w0.z, x0.z, w0.w * x0.w)));
  float s1 = fmaf(w1.x, x1.x, fmaf(w1.y, x1.y, fmaf(w1.z, x1.z, w1.w * x1.w)));
  return wreduce(s0 + s1);
}

__device__ __forceinline__ float dot512_wave(const float* __restrict__ a,
                                             const float* __restrict__ b, int lane) {
  const float4* b4 = (const float4*)b;
  return dotW(a, b4[lane], b4[lane + 64], lane);
}

__device__ __forceinline__ float dot128_wave(const float* __restrict__ a,
                                             const float* __restrict__ b, int lane) {
  const float2* a2 = (const float2*)a;
  const float2* b2 = (const float2*)b;
  float2 x = a2[lane], y = b2[lane];
  return wreduce(fmaf(x.x, y.x, x.y * y.y));
}

// ---------------- K1: one minimal task per wave, zero dependencies ----------------
#define W_OBJ_E  (Bn*MO*NOBJ)             // 3552
#define W_ACT_E  (W_OBJ_E + Bn*Kk)        // 4128
#define W_LINP_E (W_ACT_E + Bn*MO*6)      // 4704
#define W_EO_E   (W_LINP_E + NOBJ*6)      // 4926
#define W_EA_E   (W_EO_E + NACT*6)        // 4962
#define W_INV_E  (W_EA_E + NTRS)          // 4965
#define W_NE_E   (W_INV_E + Bn*NCLS)      // 7365
#define W_TOT    (W_NE_E + 38)            // 7403 (38*64=2432 >= NZERO)

__global__ __launch_bounds__(256) void k1(
    const float* __restrict__ inp, const float* __restrict__ objmask,
    const float* __restrict__ W_obj, const float* __restrict__ b_obj,
    const float* __restrict__ W_act, const float* __restrict__ b_act,
    const float* __restrict__ W_tr, const float* __restrict__ b_tr,
    const float* __restrict__ W_ne, const float* __restrict__ b_ne,
    const float* __restrict__ obj_emb, const float* __restrict__ act_emb,
    float* __restrict__ out, float* __restrict__ ws)
{
  int gt = blockIdx.x * 256 + threadIdx.x;
  int w = gt >> 6, lane = gt & 63;

  if (w < W_OBJ_E) {
    int b = w / (MO*NOBJ), r = w % (MO*NOBJ), o = r / NOBJ, c = r % NOBJ;
    float v = dot512_wave(W_obj + c*Dd, inp + (b*MO + o)*Dd, lane) + b_obj[c];
    if (!lane) { out[OUT_OBJ + (b*MO + o)*NOBJ + c] = v; ws[WS_OBJ + (b*MO + o)*NOBJ + c] = v; }
  } else if (w < W_ACT_E) {
    int r = w - W_OBJ_E, b = r / Kk, k = r % Kk, o = k / NACT, a = k % NACT;
    float v = dot512_wave(W_act + a*Dd, inp + (b*MO + o)*Dd, lane) + b_act[a];
    if (!lane) { out[OUT_ACT + b*Kk + k] = v; ws[WS_ACT + b*Kk + k] = v; }
  } else if (w < W_LINP_E) {
    int r = w - W_ACT_E, b = r / (MO*6), r2 = r % (MO*6), o = r2 / 6, th = r2 % 6;
    int t = th >> 1, h = th & 1;
    float v = dot512_wave(W_tr + t*FD + h*HALF, inp + (b*MO + o)*Dd, lane);
    if (!lane) ws[WS_LINP + (b*MO + o)*6 + th] = v;
  } else if (w < W_EO_E) {
    int r = w - W_LINP_E, oc = r / 6, th = r % 6, t = th >> 1, h = th & 1;
    float v = dot128_wave(W_tr + t*FD + h*HALF + Dd, obj_emb + oc*EMB, lane);
    if (!lane) ws[WS_EO + oc*6 + th] = v;
  } else if (w < W_INV_E) {
    if (w < W_EA_E) {
      int r = w - W_EO_E, a = r / 6, th = r % 6, t = th >> 1, h = th & 1;
      float v = dot128_wave(W_tr + t*FD + h*HALF + Dd + EMB, act_emb + a*EMB, lane);
      if (!lane) ws[WS_EA + a*6 + th] = v;
    } else {
      int t = w - W_EA_E;
      const float4* w4 = (const float4*)(W_tr + t*FD);
      float s = 0.f;
#pragma unroll
      for (int i = 0; i < 6; ++i) { float4 x = w4[lane + 64*i]; s += x.x + x.y + x.z + x.w; }
      s = wreduce(s);
      if (!lane) ws[WS_INV + t] = b_tr[t] - s;        // all-(-1) pair-row logit
    }
  } else if (w < W_NE_E) {
    // one wave per (b,c): masked-mean pool inline (L1-hot: 4 waves/block share b),
    // then W_ne dot
    int r = w - W_INV_E, b = r / NCLS, c = r % NCLS;
    const float4* i4 = (const float4*)inp;
    float msum = 0.f;
    float4 p0 = make_float4(0.f, 0.f, 0.f, 0.f), p1 = p0;
#pragma unroll
    for (int o = 0; o < MO; ++o) {
      float m = objmask[b*MO + o];
      msum += m;
      float4 v0 = i4[(b*MO + o)*128 + lane];
      float4 v1 = i4[(b*MO + o)*128 + lane + 64];
      p0.x = fmaf(m, v0.x, p0.x); p0.y = fmaf(m, v0.y, p0.y);
      p0.z = fmaf(m, v0.z, p0.z); p0.w = fmaf(m, v0.w, p0.w);
      p1.x = fmaf(m, v1.x, p1.x); p1.y = fmaf(m, v1.y, p1.y);
      p1.z = fmaf(m, v1.z, p1.z); p1.w = fmaf(m, v1.w, p1.w);
    }
    float v = dotW(W_ne + c*Dd, p0, p1, lane) / msum + b_ne[c];
    if (!lane) ws[WS_NE + b*NCLS + c] = v;
  } else if (w < W_TOT) {
    int idx = (w - W_NE_E)*64 + lane;
    if (idx < NZERO) ((unsigned*)ws)[WS_SEG + idx] = 0u;   // segmax zero-init
  }
}

// ---------------- K2: pair kernel, 160 blocks, 1 pair/thread (R2-proven) ----------
#define NSLICE 20

__global__ __launch_bounds__(256) void k2(
    const float* __restrict__ objmask, const float* __restrict__ TRt,
    const float* __restrict__ b_tr, const int* __restrict__ AA,
    const int* __restrict__ aalut,
    float* __restrict__ out, float* __restrict__ ws)
{
  __shared__ float s_L[Kk*6];              // [k][t*2+h], h==0 half includes b_tr
  __shared__ float s_inv[NTRS];
  __shared__ int s_sel[Kk], s_aa[Kk], s_C[Kk], s_pred[MO], s_T;

  int b = blockIdx.x / NSLICE, slice = blockIdx.x % NSLICE;
  int tid = threadIdx.x;

  // ---- preamble: per-block redundant argmax + selection (cheap, L2-hot) ----
  if (tid < MO) {                          // obj argmax, first-max
    const float* p = ws + WS_OBJ + (b*MO + tid)*NOBJ;
    float best = p[0]; int bi = 0;
#pragma unroll
    for (int c = 1; c < NOBJ; ++c) { float v = p[c]; if (v > best) { best = v; bi = c; } }
    s_pred[tid] = bi;
  } else if (tid >= 64 && tid < 64 + Kk) { // selection flags
    int k = tid - 64, o = k / NACT;
    int aa = AA[b*Kk + k];
    // sigmoid(x)>0.5 <=> x>0 ; pred_act==1.0 also needs mask==1.0
    int sel = (ws[WS_ACT + b*Kk + k] > 0.f) && (objmask[b*MO + o] == 1.0f) && (aa != -1);
    s_sel[k] = sel;
    s_aa[k] = sel ? aa : -1;
  } else if (tid >= 192 && tid < 192 + NTRS) {
    s_inv[tid - 192] = ws[WS_INV + (tid - 192)];
  }
  __syncthreads();
  for (int m = tid; m < Kk*6; m += 256) {  // assemble half-logits
    int k = m / 6, th = m % 6, t = th >> 1, h = th & 1;
    int o = k / NACT, a = k % NACT;
    float v = ws[WS_LINP + (b*MO + o)*6 + th] + ws[WS_EO + s_pred[o]*6 + th]
            + ws[WS_EA + a*6 + th];
    if (h == 0) v += b_tr[t];
    s_L[m] = v;
  }
  if (tid == 0) {
    int c = 0;
    for (int k = 0; k < Kk; ++k) { s_C[k] = c; c += s_sel[k]; }
    s_T = c;
  }
  __syncthreads();

  // ---- pair phase: closed-form packed destination, one pair per thread ----
  int T = s_T, Vtot = T*(T-1);
  int q = slice*256 + tid;
  if (q < Pp) {
    float* plog = out + OUT_PLOG + (size_t)b*Pp*NTRS;
    float* ttgt = out + OUT_TTGT + (size_t)b*Pp*NTRS;
    int i = q / (Kk-1);
    int jj = q - i*(Kk-1);
    int j = jj + (jj >= i ? 1 : 0);
    int si = s_sel[i], sj = s_sel[j];
    // # valid pairs strictly before (i,j) in lex order -> O(1) packed position
    int vb = s_C[i]*(T-1) + (si ? (s_C[j] - (i < j ? 1 : 0)) : 0);
    bool valid = si && sj;
    int pos = valid ? vb : (Vtot + q - vb);
    float l0, l1, l2;
    if (valid) {
      l0 = s_L[i*6+0] + s_L[j*6+1];
      l1 = s_L[i*6+2] + s_L[j*6+3];
      l2 = s_L[i*6+4] + s_L[j*6+5];
    } else { l0 = s_inv[0]; l1 = s_inv[1]; l2 = s_inv[2]; }
    int ob = pos*3;
    plog[ob+0] = l0; plog[ob+1] = l1; plog[ob+2] = l2;
    if (valid) {
      const float* tr = TRt + (((size_t)b*Kk + i)*Kk + j)*NTRS;
      ttgt[ob+0] = tr[0]; ttgt[ob+1] = tr[1]; ttgt[ob+2] = tr[2];
      int base = (s_aa[i]*NAA + s_aa[j])*NTRS;
      unsigned* seg = (unsigned*)ws + WS_SEG + b*NCLS;
      atomicMax(&seg[aalut[base+0]], fmap(l0));
      atomicMax(&seg[aalut[base+1]], fmap(l1));
      atomicMax(&seg[aalut[base+2]], fmap(l2));
    } else {
      ttgt[ob+0] = -1.f; ttgt[ob+1] = -1.f; ttgt[ob+2] = -1.f;
    }
  }
}

// ---------------- K3: final merge ----------------
__global__ __launch_bounds__(320) void k3(float* __restrict__ out,
                                          const float* __restrict__ ws)
{
  int b = blockIdx.x, c = threadIdx.x;
  if (c < NCLS) {
    unsigned u = ((const unsigned*)ws)[WS_SEG + b*NCLS + c];
    out[OUT_FINAL + b*NCLS + c] = u ? funmap(u) : ws[WS_NE + b*NCLS + c];
  }
}

extern "C" void kernel_launch(void* const* d_in, const int* in_sizes, int n_in,
                              void* d_out, int out_size, void* d_ws, size_t ws_size,
                              hipStream_t stream) {
  (void)in_sizes; (void)n_in; (void)ws_size; (void)out_size;
  const float* inp      = (const float*)d_in[0];
  const float* objmask  = (const float*)d_in[1];
  const float* TRt      = (const float*)d_in[2];
  const float* W_obj    = (const float*)d_in[3];
  const float* b_obj    = (const float*)d_in[4];
  const float* W_act    = (const float*)d_in[5];
  const float* b_act    = (const float*)d_in[6];
  const float* W_tr     = (const float*)d_in[7];
  const float* b_tr     = (const float*)d_in[8];
  const float* W_ne     = (const float*)d_in[9];
  const float* b_ne     = (const float*)d_in[10];
  const float* obj_emb  = (const float*)d_in[11];
  const float* act_emb  = (const float*)d_in[12];
  const int*   AA       = (const int*)d_in[13];
  // d_in[14] = obj_act_lookup (eval-only)
  const int*   aalut    = (const int*)d_in[15];
  float* out = (float*)d_out;
  float* ws  = (float*)d_ws;

  hipLaunchKernelGGL(k1, dim3((W_TOT + 3) / 4), dim3(256), 0, stream,
                     inp, objmask, W_obj, b_obj, W_act, b_act, W_tr, b_tr,
                     W_ne, b_ne, obj_emb, act_emb, out, ws);
  hipLaunchKernelGGL(k2, dim3(Bn * NSLICE), dim3(256), 0, stream,
                     objmask, TRt, b_tr, AA, aalut, out, ws);
  hipLaunchKernelGGL(k3, dim3(Bn), dim3(320), 0, stream, out, ws);
}

// Round 7
// 95.469 us; speedup vs baseline: 1.1493x; 1.0360x over previous
//
#include <hip/hip_runtime.h>
#include <hip/hip_bf16.h>

// ---------------- problem constants ----------------
#define Bn    8
#define MO    12
#define Dd    512
#define NOBJ  37
#define NACT  6
#define NTRS  3
#define EMB   128
#define NAA   100
#define NCLS  300
#define Kk    72            // MO*NACT
#define Pp    5112          // Kk*(Kk-1)
#define HALF  768           // Dd + 2*EMB
#define FD    1536          // 2*HALF

// output layout (concatenated return order)
#define OUT_FINAL 0
#define OUT_PLOG  (Bn*NCLS)                       // 2400
#define OUT_TTGT  (OUT_PLOG + Bn*Pp*NTRS)         // 125088
#define OUT_ACT   (OUT_TTGT + Bn*Pp*NTRS)         // 247776
#define OUT_OBJ   (OUT_ACT + Bn*Kk)               // 248352

// ---------------- workspace layout (4-byte units) ----------------
#define WS_LINP 0                                 // [B,MO,6] (th = t*2+h)
#define WS_EO   (WS_LINP + Bn*MO*6)               // [NOBJ,6]        576
#define WS_EA   (WS_EO + NOBJ*6)                  // [NACT,6]        798
#define WS_INV  (WS_EA + NACT*6)                  // [3]             834
#define WS_NE   840                               // [B,NCLS]
#define WS_OBJ  (WS_NE + Bn*NCLS)                 // [B,MO,NOBJ]    3240
#define WS_ACT  (WS_OBJ + Bn*MO*NOBJ)             // [B,K]          6792

// monotonic float <-> uint; 0u is below any finite mapped value = "empty"
__device__ __forceinline__ unsigned fmap(float f) {
  unsigned u = __float_as_uint(f);
  return (u & 0x80000000u) ? ~u : (u | 0x80000000u);
}
__device__ __forceinline__ float funmap(unsigned u) {
  return __uint_as_float((u & 0x80000000u) ? (u & 0x7fffffffu) : ~u);
}

__device__ __forceinline__ float wreduce(float v) {
#pragma unroll
  for (int off = 32; off > 0; off >>= 1) v += __shfl_xor(v, off, 64);
  return v;
}

// 512-dot with x preloaded (lane holds float4 #lane, #(lane+64))
__device__ __forceinline__ float dotW(const float* __restrict__ wrow,
                                      float4 x0, float4 x1, int lane) {
  const float4* w4 = (const float4*)wrow;
  float4 w0 = w4[lane], w1 = w4[lane + 64];
  float s0 = fmaf(w0.x, x0.x, fmaf(w0.y, x0.y, fmaf(w0.z, x0.z, w0.w * x0.w)));
  float s1 = fmaf(w1.x, x1.x, fmaf(w1.y, x1.y, fmaf(w1.z, x1.z, w1.w * x1.w)));
  return wreduce(s0 + s1);
}

__device__ __forceinline__ float dot512_wave(const float* __restrict__ a,
                                             const float* __restrict__ b, int lane) {
  const float4* b4 = (const float4*)b;
  return dotW(a, b4[lane], b4[lane + 64], lane);
}

__device__ __forceinline__ float dot128_wave(const float* __restrict__ a,
                                             const float* __restrict__ b, int lane) {
  const float2* a2 = (const float2*)a;
  const float2* b2 = (const float2*)b;
  float2 x = a2[lane], y = b2[lane];
  return wreduce(fmaf(x.x, y.x, x.y * y.y));
}

// ---------------- K1: one minimal task per wave, zero dependencies ----------------
#define W_OBJ_E  (Bn*MO*NOBJ)             // 3552
#define W_ACT_E  (W_OBJ_E + Bn*Kk)        // 4128
#define W_LINP_E (W_ACT_E + Bn*MO*6)      // 4704
#define W_EO_E   (W_LINP_E + NOBJ*6)      // 4926
#define W_EA_E   (W_EO_E + NACT*6)        // 4962
#define W_INV_E  (W_EA_E + NTRS)          // 4965
#define W_TOT    (W_INV_E + Bn*NCLS)      // 7365

__global__ __launch_bounds__(256) void k1(
    const float* __restrict__ inp, const float* __restrict__ objmask,
    const float* __restrict__ W_obj, const float* __restrict__ b_obj,
    const float* __restrict__ W_act, const float* __restrict__ b_act,
    const float* __restrict__ W_tr, const float* __restrict__ b_tr,
    const float* __restrict__ W_ne, const float* __restrict__ b_ne,
    const float* __restrict__ obj_emb, const float* __restrict__ act_emb,
    float* __restrict__ out, float* __restrict__ ws)
{
  int gt = blockIdx.x * 256 + threadIdx.x;
  int w = gt >> 6, lane = gt & 63;

  if (w < W_OBJ_E) {
    int b = w / (MO*NOBJ), r = w % (MO*NOBJ), o = r / NOBJ, c = r % NOBJ;
    float v = dot512_wave(W_obj + c*Dd, inp + (b*MO + o)*Dd, lane) + b_obj[c];
    if (!lane) { out[OUT_OBJ + (b*MO + o)*NOBJ + c] = v; ws[WS_OBJ + (b*MO + o)*NOBJ + c] = v; }
  } else if (w < W_ACT_E) {
    int r = w - W_OBJ_E, b = r / Kk, k = r % Kk, o = k / NACT, a = k % NACT;
    float v = dot512_wave(W_act + a*Dd, inp + (b*MO + o)*Dd, lane) + b_act[a];
    if (!lane) { out[OUT_ACT + b*Kk + k] = v; ws[WS_ACT + b*Kk + k] = v; }
  } else if (w < W_LINP_E) {
    int r = w - W_ACT_E, b = r / (MO*6), r2 = r % (MO*6), o = r2 / 6, th = r2 % 6;
    int t = th >> 1, h = th & 1;
    float v = dot512_wave(W_tr + t*FD + h*HALF, inp + (b*MO + o)*Dd, lane);
    if (!lane) ws[WS_LINP + (b*MO + o)*6 + th] = v;
  } else if (w < W_EO_E) {
    int r = w - W_LINP_E, oc = r / 6, th = r % 6, t = th >> 1, h = th & 1;
    float v = dot128_wave(W_tr + t*FD + h*HALF + Dd, obj_emb + oc*EMB, lane);
    if (!lane) ws[WS_EO + oc*6 + th] = v;
  } else if (w < W_INV_E) {
    if (w < W_EA_E) {
      int r = w - W_EO_E, a = r / 6, th = r % 6, t = th >> 1, h = th & 1;
      float v = dot128_wave(W_tr + t*FD + h*HALF + Dd + EMB, act_emb + a*EMB, lane);
      if (!lane) ws[WS_EA + a*6 + th] = v;
    } else {
      int t = w - W_EA_E;
      const float4* w4 = (const float4*)(W_tr + t*FD);
      float s = 0.f;
#pragma unroll
      for (int i = 0; i < 6; ++i) { float4 x = w4[lane + 64*i]; s += x.x + x.y + x.z + x.w; }
      s = wreduce(s);
      if (!lane) ws[WS_INV + t] = b_tr[t] - s;        // all-(-1) pair-row logit
    }
  } else if (w < W_TOT) {
    // one wave per (b,c): masked-mean pool inline (L1-hot: waves sharing b),
    // then W_ne dot
    int r = w - W_INV_E, b = r / NCLS, c = r % NCLS;
    const float4* i4 = (const float4*)inp;
    float msum = 0.f;
    float4 p0 = make_float4(0.f, 0.f, 0.f, 0.f), p1 = p0;
#pragma unroll
    for (int o = 0; o < MO; ++o) {
      float m = objmask[b*MO + o];
      msum += m;
      float4 v0 = i4[(b*MO + o)*128 + lane];
      float4 v1 = i4[(b*MO + o)*128 + lane + 64];
      p0.x = fmaf(m, v0.x, p0.x); p0.y = fmaf(m, v0.y, p0.y);
      p0.z = fmaf(m, v0.z, p0.z); p0.w = fmaf(m, v0.w, p0.w);
      p1.x = fmaf(m, v1.x, p1.x); p1.y = fmaf(m, v1.y, p1.y);
      p1.z = fmaf(m, v1.z, p1.z); p1.w = fmaf(m, v1.w, p1.w);
    }
    float v = dotW(W_ne + c*Dd, p0, p1, lane) / msum + b_ne[c];
    if (!lane) ws[WS_NE + b*NCLS + c] = v;
  }
}

// ---------------- K2: pair blocks (slice 0..19) + concurrent merge block (20) ----
// Merge depends only on K1 outputs (sel/aa/L/ne) -> runs in parallel with pair
// blocks; LDS segmax over valid pairs only; no fences, no global atomics.
#define NSLICE 20

__global__ __launch_bounds__(256) void k2(
    const float* __restrict__ objmask, const float* __restrict__ TRt,
    const float* __restrict__ b_tr, const int* __restrict__ AA,
    const int* __restrict__ aalut,
    float* __restrict__ out, float* __restrict__ ws)
{
  __shared__ float s_L[Kk*6];              // [k][t*2+h], h==0 half includes b_tr
  __shared__ float s_inv[NTRS];
  __shared__ unsigned s_seg[NCLS];
  __shared__ int s_sel[Kk], s_aa[Kk], s_C[Kk], s_vlist[Kk], s_pred[MO], s_T;

  int b = blockIdx.x / (NSLICE + 1), slice = blockIdx.x % (NSLICE + 1);
  int tid = threadIdx.x;

  // ---- preamble: per-block redundant argmax + selection (cheap, L2-hot) ----
  if (tid < MO) {                          // obj argmax, first-max
    const float* p = ws + WS_OBJ + (b*MO + tid)*NOBJ;
    float best = p[0]; int bi = 0;
#pragma unroll
    for (int c = 1; c < NOBJ; ++c) { float v = p[c]; if (v > best) { best = v; bi = c; } }
    s_pred[tid] = bi;
  } else if (tid >= 64 && tid < 64 + Kk) { // selection flags
    int k = tid - 64, o = k / NACT;
    int aa = AA[b*Kk + k];
    // sigmoid(x)>0.5 <=> x>0 ; pred_act==1.0 also needs mask==1.0
    int sel = (ws[WS_ACT + b*Kk + k] > 0.f) && (objmask[b*MO + o] == 1.0f) && (aa != -1);
    s_sel[k] = sel;
    s_aa[k] = sel ? aa : -1;
  } else if (tid >= 192 && tid < 192 + NTRS) {
    s_inv[tid - 192] = ws[WS_INV + (tid - 192)];
  }
  __syncthreads();
  for (int m = tid; m < Kk*6; m += 256) {  // assemble half-logits
    int k = m / 6, th = m % 6, t = th >> 1, h = th & 1;
    int o = k / NACT, a = k % NACT;
    float v = ws[WS_LINP + (b*MO + o)*6 + th] + ws[WS_EO + s_pred[o]*6 + th]
            + ws[WS_EA + a*6 + th];
    if (h == 0) v += b_tr[t];
    s_L[m] = v;
  }
  if (tid == 0) {
    int c = 0;
    for (int k = 0; k < Kk; ++k) { s_C[k] = c; c += s_sel[k]; }
    s_T = c;
  }
  __syncthreads();

  int T = s_T, Vtot = T*(T-1);

  if (slice < NSLICE) {
    // ---- pair block: closed-form packed destination, one pair per thread ----
    int q = slice*256 + tid;
    if (q < Pp) {
      float* plog = out + OUT_PLOG + (size_t)b*Pp*NTRS;
      float* ttgt = out + OUT_TTGT + (size_t)b*Pp*NTRS;
      int i = q / (Kk-1);
      int jj = q - i*(Kk-1);
      int j = jj + (jj >= i ? 1 : 0);
      int si = s_sel[i], sj = s_sel[j];
      // # valid pairs strictly before (i,j) in lex order -> O(1) packed position
      int vb = s_C[i]*(T-1) + (si ? (s_C[j] - (i < j ? 1 : 0)) : 0);
      bool valid = si && sj;
      int pos = valid ? vb : (Vtot + q - vb);
      float l0, l1, l2;
      if (valid) {
        l0 = s_L[i*6+0] + s_L[j*6+1];
        l1 = s_L[i*6+2] + s_L[j*6+3];
        l2 = s_L[i*6+4] + s_L[j*6+5];
      } else { l0 = s_inv[0]; l1 = s_inv[1]; l2 = s_inv[2]; }
      int ob = pos*3;
      plog[ob+0] = l0; plog[ob+1] = l1; plog[ob+2] = l2;
      if (valid) {
        const float* tr = TRt + (((size_t)b*Kk + i)*Kk + j)*NTRS;
        ttgt[ob+0] = tr[0]; ttgt[ob+1] = tr[1]; ttgt[ob+2] = tr[2];
      } else {
        ttgt[ob+0] = -1.f; ttgt[ob+1] = -1.f; ttgt[ob+2] = -1.f;
      }
    }
  } else {
    // ---- merge block: LDS segmax over VALID pairs only (T(T-1) ~ 1300 avg) ----
    if (tid < Kk && s_sel[tid]) s_vlist[s_C[tid]] = tid;
    for (int c = tid; c < NCLS; c += 256) s_seg[c] = 0u;
    __syncthreads();
    for (int m = tid; m < Vtot; m += 256) {
      int vi = m / (T-1);
      int r = m - vi*(T-1);
      int vj = r + (r >= vi ? 1 : 0);
      int i = s_vlist[vi], j = s_vlist[vj];
      float l0 = s_L[i*6+0] + s_L[j*6+1];
      float l1 = s_L[i*6+2] + s_L[j*6+3];
      float l2 = s_L[i*6+4] + s_L[j*6+5];
      int base = (s_aa[i]*NAA + s_aa[j])*NTRS;
      atomicMax(&s_seg[aalut[base+0]], fmap(l0));   // ds_max, LDS-local
      atomicMax(&s_seg[aalut[base+1]], fmap(l1));
      atomicMax(&s_seg[aalut[base+2]], fmap(l2));
    }
    __syncthreads();
    for (int c = tid; c < NCLS; c += 256) {
      unsigned u = s_seg[c];
      out[OUT_FINAL + b*NCLS + c] = u ? funmap(u) : ws[WS_NE + b*NCLS + c];
    }
  }
}

extern "C" void kernel_launch(void* const* d_in, const int* in_sizes, int n_in,
                              void* d_out, int out_size, void* d_ws, size_t ws_size,
                              hipStream_t stream) {
  (void)in_sizes; (void)n_in; (void)ws_size; (void)out_size;
  const float* inp      = (const float*)d_in[0];
  const float* objmask  = (const float*)d_in[1];
  const float* TRt      = (const float*)d_in[2];
  const float* W_obj    = (const float*)d_in[3];
  const float* b_obj    = (const float*)d_in[4];
  const float* W_act    = (const float*)d_in[5];
  const float* b_act    = (const float*)d_in[6];
  const float* W_tr     = (const float*)d_in[7];
  const float* b_tr     = (const float*)d_in[8];
  const float* W_ne     = (const float*)d_in[9];
  const float* b_ne     = (const float*)d_in[10];
  const float* obj_emb  = (const float*)d_in[11];
  const float* act_emb  = (const float*)d_in[12];
  const int*   AA       = (const int*)d_in[13];
  // d_in[14] = obj_act_lookup (eval-only)
  const int*   aalut    = (const int*)d_in[15];
  float* out = (float*)d_out;
  float* ws  = (float*)d_ws;

  hipLaunchKernelGGL(k1, dim3((W_TOT + 3) / 4), dim3(256), 0, stream,
                     inp, objmask, W_obj, b_obj, W_act, b_act, W_tr, b_tr,
                     W_ne, b_ne, obj_emb, act_emb, out, ws);
  hipLaunchKernelGGL(k2, dim3(Bn * (NSLICE + 1)), dim3(256), 0, stream,
                     objmask, TRt, b_tr, AA, aalut, out, ws);
}